// Round 12
// baseline (334.245 us; speedup 1.0000x reference)
//
#include <hip/hip_runtime.h>
#include <hip/hip_bf16.h>
#include <hip/hip_fp8.h>
#include <math.h>

#define M_TOT 4096
#define K_TOT 1024
#define V_TOT 32000

typedef int int4v __attribute__((ext_vector_type(4)));
typedef int int8v __attribute__((ext_vector_type(8)));
typedef float f32x4 __attribute__((ext_vector_type(4)));

__device__ __forceinline__ void gload_lds16(const void* g, void* l) {
  __builtin_amdgcn_global_load_lds(
      (const __attribute__((address_space(1))) void*)g,
      (__attribute__((address_space(3))) void*)l, 16, 0, 0);
}

__device__ __forceinline__ float sani(float v) {
  return (v != v) ? 0.0f : fminf(fmaxf(v, -1e4f), 1e4f);
}

__device__ __forceinline__ int pk4_fp8(float a, float b, float c, float d) {
#if __has_builtin(__builtin_amdgcn_cvt_pk_fp8_f32)
  int p = __builtin_amdgcn_cvt_pk_fp8_f32(a, b, 0, false);
  p = __builtin_amdgcn_cvt_pk_fp8_f32(c, d, p, true);
  return p;
#else
  union { unsigned char b4[4]; int i; } u;
  u.b4[0] = __hip_fp8_e4m3(a).__x;
  u.b4[1] = __hip_fp8_e4m3(b).__x;
  u.b4[2] = __hip_fp8_e4m3(c).__x;
  u.b4[3] = __hip_fp8_e4m3(d).__x;
  return u.i;
#endif
}

__global__ void prep_h(const float* __restrict__ h, unsigned char* __restrict__ h8,
                       float* __restrict__ h0) {
  int m = blockIdx.x;
  int t = threadIdx.x;
  const float* row = h + (long)m * (K_TOT + 1);
  if (t == 0) h0[m] = sani(row[0]);
  float4 x = *(const float4*)(row + 1 + t * 4);
  ((int*)(h8 + (long)m * K_TOT))[t] =
      pk4_fp8(sani(x.x), sani(x.y), sani(x.z), sani(x.w));
}

__global__ void prep_w(const float* __restrict__ w, unsigned char* __restrict__ w8,
                       float* __restrict__ wtime) {
  __shared__ float red[4];
  __shared__ float r_sh;
  int v = blockIdx.x;
  int t = threadIdx.x;
  const float* row = w + (long)v * K_TOT;
  float4 x = *(const float4*)(row + t * 4);
  float s = x.x * x.x + x.y * x.y + x.z * x.z + x.w * x.w;
#pragma unroll
  for (int off = 32; off > 0; off >>= 1) s += __shfl_down(s, off);
  int lane = t & 63, wv = t >> 6;
  if (lane == 0) red[wv] = s;
  __syncthreads();
  if (t == 0) {
    float tot = red[0] + red[1] + red[2] + red[3];
    float norm = sqrtf(tot);
    float r = (norm > 1e-7f) ? (sinhf(norm) / fmaxf(norm, 1e-7f)) : 1.0f;
    r_sh = r;
    wtime[v] = coshf(norm);
  }
  __syncthreads();
  float sc = 16.0f * r_sh;
  ((int*)(w8 + (long)v * K_TOT))[t] =
      pk4_fp8(sc * x.x, sc * x.y, sc * x.z, sc * x.w);
}

// ====== persistent-panel MX-fp8 GEMM: 250 blocks x 16 tiles of 128x256 =====
// Each block: fixed v-panel (256 cols), 16 m-tiles of 128 rows. Ping-pong
// acc banks (accA/accB, 64+64 regs): while tile N accumulates into bank X,
// bank Y (tile N-1) is transformed + stored 2xfloat4 PER K-ITER (static
// chunk = unrolled kt, rule #20) -> the 128KB/tile store drain overlaps the
// next tile's K-loop instead of idling the CU (r11's ~26k-cyc naked tail).
// LDS: 3 x 48KB buffers (A 16KB rows0-127 + B 32KB rows0-255), BK=128 fp8.
// Zero-conflict XOR swizzle (r4-r11 measured 0): slot chunk c holds global
// chunk c^(row&7); source pre-swizzled cc=(t&7)^((t>>3)&7); read chunk
// (2fq+h)^(fr&7). Both sides, same involution (rule #21).
// vmcnt LEDGER (ops/iter order [pre(4 h0, kt==0 only)], S=stage(6), st(2)):
//   boundary of iter g proves stage(g+1) (issued iter g-1):
//   allowed-outstanding = st(g-1) + pre(g) + S(g) + st(g)
//   tile0 (no st): 6 -> VM6 | tile1 kt0: 0+4+6+2=12 -> VM12
//   tile>=2 kt0: 2+4+6+2=14 -> VM14 | steady kt>0: 2+6+2=10 -> VM10
//   Old store chunks (16KB/CU) fall out of the window after 2 iters (~4k cyc
//   >> 1.6k drain). vmem ops cannot cross iteration boundaries (VMC asm has
//   "memory" clobber) so source-order inside an iter is count-irrelevant.
//   Prologue ends vmcnt(0) so its load order doesn't matter.
// 3-buffer overwrite safety: iter g stages into buf (g+2)%3, which held tile
// g-1, last read at iter g-1, sealed by that iter's boundary BAR; ds_reads
// feeding MFMAs complete before the wave reaches BAR (compiler lgkmcnt).
// launch_bounds(512,2): VGPR cap 256 (acc 128 + ~100 live). (512,4) would
// cap at 64 -> acc spill -> r4's 13.9GB disaster. 1 block/CU (LDS 144KB).
#define BAR __builtin_amdgcn_s_barrier()
#define VMC(N) asm volatile("s_waitcnt vmcnt(" #N ")" ::: "memory")

#define STORE_CHUNK(KT, ACCO, H0O)                                            \
  {                                                                           \
    const int imo = (KT) >> 1;                                                \
    const int iv0 = ((KT) & 1) * 2;                                           \
    float* obase_ = orow_old + imo * (16L * V_TOT);                           \
    _Pragma("unroll") for (int dv = 0; dv < 2; ++dv) {                        \
      const int iv = iv0 + dv;                                                \
      f32x4 rr;                                                               \
      _Pragma("unroll") for (int j = 0; j < 4; ++j) {                         \
        float x = fmaf(H0O[imo], wt4[iv][j], -ACCO[imo][iv][j]);              \
        float xm1 = fmaxf(x - 1.0f, 0.0f);                                    \
        float arg = fmaxf(fmaf(x, x, -1.0f), 0.0f);                           \
        float lg2 = __builtin_amdgcn_logf(x + __builtin_amdgcn_sqrtf(arg));   \
        float dex = 0.69314718055994531f * lg2;                               \
        float d2e = dex * dex;                                                \
        float ts = fmaf(xm1, -1.0f / 12.0f, 1.0f);                            \
        float d2t = 2.0f * xm1 * ts * ts;                                     \
        rr[j] = ntau * ((xm1 < 1e-3f) ? d2t : d2e);                           \
      }                                                                       \
      *(f32x4*)(obase_ + iv * 16 + fq * 4) = rr;                              \
      ACCO[imo][iv] = (f32x4)(0.0f);                                          \
    }                                                                         \
  }

#define KITER(KT, DO_PRE, H0N, ACC, DO_ST, ACCO, H0O, VMN)                    \
  {                                                                           \
    if (DO_PRE) {                                                             \
      _Pragma("unroll") for (int im = 0; im < 4; ++im)                        \
          H0N[im] = h0p[im * 16];                                             \
    }                                                                         \
    int gs = g + (KT) + 2;                                                    \
    if (gs > 127) gs = 127;                                                   \
    STAGE(gs, sbv);                                                           \
    if (DO_ST) { STORE_CHUNK(KT, ACCO, H0O); }                                \
    const int CBO = cbv * 49152;                                              \
    int8v bv0 = RDF(CBO + b_rd);                                              \
    int8v bv1 = RDF(CBO + b_rd + 2048);                                       \
    int8v bv2 = RDF(CBO + b_rd + 4096);                                       \
    int8v bv3 = RDF(CBO + b_rd + 6144);                                       \
    __builtin_amdgcn_s_setprio(1);                                            \
    _Pragma("unroll") for (int im = 0; im < 4; ++im) {                        \
      int8v av = RDF(CBO + a_rd + im * 2048);                                 \
      ACC[im][0] = __builtin_amdgcn_mfma_scale_f32_16x16x128_f8f6f4(          \
          bv0, av, ACC[im][0], 0, 0, 0, 0x7B7B7B7B, 0, 0x7F7F7F7F);           \
      ACC[im][1] = __builtin_amdgcn_mfma_scale_f32_16x16x128_f8f6f4(          \
          bv1, av, ACC[im][1], 0, 0, 0, 0x7B7B7B7B, 0, 0x7F7F7F7F);           \
      ACC[im][2] = __builtin_amdgcn_mfma_scale_f32_16x16x128_f8f6f4(          \
          bv2, av, ACC[im][2], 0, 0, 0, 0x7B7B7B7B, 0, 0x7F7F7F7F);           \
      ACC[im][3] = __builtin_amdgcn_mfma_scale_f32_16x16x128_f8f6f4(          \
          bv3, av, ACC[im][3], 0, 0, 0, 0x7B7B7B7B, 0, 0x7F7F7F7F);           \
    }                                                                         \
    __builtin_amdgcn_s_setprio(0);                                            \
    VMC(VMN);                                                                 \
    BAR;                                                                      \
    cbv = (cbv == 2) ? 0 : cbv + 1;                                           \
    sbv = (sbv == 2) ? 0 : sbv + 1;                                           \
  }

#define KT8(DO_PRE, H0N, ACC, DO_ST, ACCO, H0O, VM0, VMR)                     \
  KITER(0, DO_PRE, H0N, ACC, DO_ST, ACCO, H0O, VM0)                           \
  KITER(1, 0, H0N, ACC, DO_ST, ACCO, H0O, VMR)                                \
  KITER(2, 0, H0N, ACC, DO_ST, ACCO, H0O, VMR)                                \
  KITER(3, 0, H0N, ACC, DO_ST, ACCO, H0O, VMR)                                \
  KITER(4, 0, H0N, ACC, DO_ST, ACCO, H0O, VMR)                                \
  KITER(5, 0, H0N, ACC, DO_ST, ACCO, H0O, VMR)                                \
  KITER(6, 0, H0N, ACC, DO_ST, ACCO, H0O, VMR)                                \
  KITER(7, 0, H0N, ACC, DO_ST, ACCO, H0O, VMR)

__global__ __launch_bounds__(512, 2) void gemm_geo(
    const unsigned char* __restrict__ h8, const unsigned char* __restrict__ w8,
    const float* __restrict__ h0, const float* __restrict__ wtime,
    const float* __restrict__ ls, float* __restrict__ out) {
  __shared__ __align__(16) char smem[147456];  // 3 x 48KB

  const int t = threadIdx.x;
  const int wave = t >> 6, lane = t & 63;
  const int fr = lane & 15, fq = lane >> 4;
  const int wm = wave >> 2, wn = wave & 3;  // 2 (M) x 4 (N) wave grid

  const int bid = blockIdx.x;
  const int p = bid >> 1;          // v-panel 0..124
  const int q = bid & 1;           // m-half
  const int col0 = p * 256;
  const int mrow_base = q * 2048;

  // read-side lane constants (bytes)
  const int xorv = fr & 7;
  const int c0 = ((2 * fq) ^ xorv) * 16;
  const int c1 = ((2 * fq + 1) ^ xorv) * 16;
  const int a_rd = (wm * 64 + fr) * 128;           // + cbv*49152 + im*2048
  const int b_rd = 16384 + (wn * 64 + fr) * 128;   // + cbv*49152 + iv*2048

  auto RDF = [&](int off) -> int8v {
    int4v lo = *(const int4v*)(smem + off + c0);
    int4v hi = *(const int4v*)(smem + off + c1);
    return (int8v){lo[0], lo[1], lo[2], lo[3], hi[0], hi[1], hi[2], hi[3]};
  };

  // staging: thread t -> row t>>3 (+64/batch), slot chunk t&7, pre-swizzled
  const int cc = (t & 7) ^ ((t >> 3) & 7);
  const unsigned char* pA = h8 + ((long)mrow_base + (t >> 3)) * K_TOT + cc * 16;
  const unsigned char* pB = w8 + ((long)col0 + (t >> 3)) * K_TOT + cc * 16;
  const int dst_w = wave * 1024;  // wave-uniform; HW adds lane*16

  auto STAGE = [&](int gg, int sb) {
    const int itv = gg >> 3, ktv = gg & 7;
    const unsigned char* a = pA + (long)itv * (128L * K_TOT) + ktv * 128;
    const unsigned char* b = pB + ktv * 128;
    const int bo = sb * 49152;
#pragma unroll
    for (int hh = 0; hh < 2; ++hh)
      gload_lds16(a + (long)hh * (64L * K_TOT), smem + bo + hh * 8192 + dst_w);
#pragma unroll
    for (int hh = 0; hh < 4; ++hh)
      gload_lds16(b + (long)hh * (64L * K_TOT),
                  smem + bo + 16384 + hh * 8192 + dst_w);
  };

  // per-block constants
  const float ntau = -fminf(fmaxf(ls[0], 0.01f), 2.5f);
  f32x4 wt4[4];
#pragma unroll
  for (int iv = 0; iv < 4; ++iv)
    wt4[iv] = *(const f32x4*)&wtime[col0 + wn * 64 + iv * 16 + fq * 4];

  f32x4 accA[4][4], accB[4][4];
#pragma unroll
  for (int i = 0; i < 4; ++i)
#pragma unroll
    for (int j = 0; j < 4; ++j) {
      accA[i][j] = (f32x4)(0.0f);
      accB[i][j] = (f32x4)(0.0f);
    }
  float h0A[4], h0B[4];

  // prologue: h0(tile0), stage flat-tiles 0,1 -> bufs 0,1; full drain once.
  const float* h0p = h0 + mrow_base + wm * 64 + fr;
#pragma unroll
  for (int im = 0; im < 4; ++im) h0A[im] = h0p[im * 16];
  STAGE(0, 0);
  STAGE(1, 1);
  VMC(0);
  BAR;

  int cbv = 0, sbv = 2;
  int g = 0;
  float* orow_old;

  // ---- tile 0: accumulate accA, no stores ----
  KT8(0, h0A, accA, 0, accB, h0B, 6, 6)
  g = 8;

  // ---- tile 1: accumulate accB, store tile0 (accA,h0A) ----
  h0p = h0 + mrow_base + 128 + wm * 64 + fr;
  orow_old = out + ((long)(mrow_base + wm * 64 + fr)) * V_TOT + col0 + wn * 64;
  KT8(1, h0B, accB, 1, accA, h0A, 12, 10)
  g = 16;

  // ---- tiles 2..15 ----
#pragma unroll 1
  for (int ith = 1; ith <= 7; ++ith) {
    const int ite = 2 * ith;
    h0p = h0 + mrow_base + ite * 128 + wm * 64 + fr;
    orow_old = out +
               ((long)(mrow_base + (ite - 1) * 128 + wm * 64 + fr)) * V_TOT +
               col0 + wn * 64;
    KT8(1, h0A, accA, 1, accB, h0B, 14, 10)
    g += 8;

    h0p = h0 + mrow_base + (ite + 1) * 128 + wm * 64 + fr;
    orow_old = out + ((long)(mrow_base + ite * 128 + wm * 64 + fr)) * V_TOT +
               col0 + wn * 64;
    KT8(1, h0B, accB, 1, accA, h0A, 14, 10)
    g += 8;
  }

  // ---- tail: tile15's own output (accB, h0B) ----
  {
    float* orow = out +
                  ((long)(mrow_base + 15 * 128 + wm * 64 + fr)) * V_TOT +
                  col0 + wn * 64;
#pragma unroll
    for (int im = 0; im < 4; ++im) {
      float* obase = orow + im * (16L * V_TOT);
#pragma unroll
      for (int iv = 0; iv < 4; ++iv) {
        f32x4 rr;
#pragma unroll
        for (int j = 0; j < 4; ++j) {
          float x = fmaf(h0B[im], wt4[iv][j], -accB[im][iv][j]);
          float xm1 = fmaxf(x - 1.0f, 0.0f);
          float arg = fmaxf(fmaf(x, x, -1.0f), 0.0f);
          float lg2 = __builtin_amdgcn_logf(x + __builtin_amdgcn_sqrtf(arg));
          float dex = 0.69314718055994531f * lg2;
          float d2e = dex * dex;
          float ts = fmaf(xm1, -1.0f / 12.0f, 1.0f);
          float d2t = 2.0f * xm1 * ts * ts;
          rr[j] = ntau * ((xm1 < 1e-3f) ? d2t : d2e);
        }
        *(f32x4*)(obase + iv * 16 + fq * 4) = rr;
      }
    }
  }
}

extern "C" void kernel_launch(void* const* d_in, const int* in_sizes, int n_in,
                              void* d_out, int out_size, void* d_ws, size_t ws_size,
                              hipStream_t stream) {
  const float* h = (const float*)d_in[0];   // [2,2048,1025]
  const float* w = (const float*)d_in[1];   // [32000,1024]
  const float* ls = (const float*)d_in[2];  // scalar
  float* out = (float*)d_out;               // [2,2048,32000] fp32

  char* ws = (char*)d_ws;
  unsigned char* w8 = (unsigned char*)ws;                     // 32,768,000 B
  unsigned char* h8 = (unsigned char*)(ws + 32768000);        // 4,194,304 B
  float* wtime = (float*)(ws + 32768000 + 4194304);           // 128,000 B
  float* h0 = (float*)(ws + 32768000 + 4194304 + 128000);     // 16,384 B

  prep_h<<<M_TOT, 256, 0, stream>>>(h, h8, h0);
  prep_w<<<V_TOT, 256, 0, stream>>>(w, w8, wtime);
  gemm_geo<<<250, 512, 0, stream>>>(h8, w8, h0, wtime, ls, out);
}

// Round 13
// 331.055 us; speedup vs baseline: 1.0096x; 1.0096x over previous
//
#include <hip/hip_runtime.h>
#include <hip/hip_bf16.h>
#include <hip/hip_fp8.h>
#include <math.h>

#define M_TOT 4096
#define K_TOT 1024
#define V_TOT 32000

typedef int int4v __attribute__((ext_vector_type(4)));
typedef int int8v __attribute__((ext_vector_type(8)));
typedef float f32x4 __attribute__((ext_vector_type(4)));

__device__ __forceinline__ void gload_lds16(const void* g, void* l) {
  __builtin_amdgcn_global_load_lds(
      (const __attribute__((address_space(1))) void*)g,
      (__attribute__((address_space(3))) void*)l, 16, 0, 0);
}

__device__ __forceinline__ float sani(float v) {
  return (v != v) ? 0.0f : fminf(fmaxf(v, -1e4f), 1e4f);
}

__device__ __forceinline__ int pk4_fp8(float a, float b, float c, float d) {
#if __has_builtin(__builtin_amdgcn_cvt_pk_fp8_f32)
  int p = __builtin_amdgcn_cvt_pk_fp8_f32(a, b, 0, false);
  p = __builtin_amdgcn_cvt_pk_fp8_f32(c, d, p, true);
  return p;
#else
  union { unsigned char b4[4]; int i; } u;
  u.b4[0] = __hip_fp8_e4m3(a).__x;
  u.b4[1] = __hip_fp8_e4m3(b).__x;
  u.b4[2] = __hip_fp8_e4m3(c).__x;
  u.b4[3] = __hip_fp8_e4m3(d).__x;
  return u.i;
#endif
}

__global__ void prep_h(const float* __restrict__ h, unsigned char* __restrict__ h8,
                       float* __restrict__ h0) {
  int m = blockIdx.x;
  int t = threadIdx.x;
  const float* row = h + (long)m * (K_TOT + 1);
  if (t == 0) h0[m] = sani(row[0]);
  float4 x = *(const float4*)(row + 1 + t * 4);
  ((int*)(h8 + (long)m * K_TOT))[t] =
      pk4_fp8(sani(x.x), sani(x.y), sani(x.z), sani(x.w));
}

__global__ void prep_w(const float* __restrict__ w, unsigned char* __restrict__ w8,
                       float* __restrict__ wtime) {
  __shared__ float red[4];
  __shared__ float r_sh;
  int v = blockIdx.x;
  int t = threadIdx.x;
  const float* row = w + (long)v * K_TOT;
  float4 x = *(const float4*)(row + t * 4);
  float s = x.x * x.x + x.y * x.y + x.z * x.z + x.w * x.w;
#pragma unroll
  for (int off = 32; off > 0; off >>= 1) s += __shfl_down(s, off);
  int lane = t & 63, wv = t >> 6;
  if (lane == 0) red[wv] = s;
  __syncthreads();
  if (t == 0) {
    float tot = red[0] + red[1] + red[2] + red[3];
    float norm = sqrtf(tot);
    float r = (norm > 1e-7f) ? (sinhf(norm) / fmaxf(norm, 1e-7f)) : 1.0f;
    r_sh = r;
    wtime[v] = coshf(norm);
  }
  __syncthreads();
  float sc = 16.0f * r_sh;
  ((int*)(w8 + (long)v * K_TOT))[t] =
      pk4_fp8(sc * x.x, sc * x.y, sc * x.z, sc * x.w);
}

// ====== 128x128 tile, BK=128, MX-fp8, 2 blocks/CU (r11 loop halved) ========
// r12 lesson: interleaving stores inside the K-loop broke the zero-conflict
// scheduling AND persistent panels lost L2 reuse -> revert to r11's loop.
// r11 lesson: at 1 block/CU the epilogue store drain (~6.5k cyc) and the
// prologue fill are naked. Fix here: halve the tile so LDS = 2 bufs x 32KB
// = 64KB -> TWO independent blocks/CU: block A's epilogue overlaps block
// B's K-loop; 8000-block turnover keeps this continuous.
// LDS: buf*32768 + {A: row*128 + c*16, rows 0..127} + {B: 16384 + same}.
// Zero-conflict swizzle (r11 measured ~0): slot chunk c holds global chunk
// c^(row&7); staging source pre-swizzled cc=(t&7)^((t>>3)&7) (gload_lds
// writes linearly, rule #21); read chunks (2fq+h)^(fr&7).
// Loop (8 iters, = r11): reads(bv4+av2) -> MFMA m0-1 -> reads av2(m2-3) ->
// lgkm0 + sched_barrier + BAR (all waves done reading buf cb) -> STAGE tile
// kt+2 into cb (write-after-read safe) -> MFMA m2-3 -> VM8 (proves kt+1;
// kt+2's 8 loads stay in flight) -> BAR.
// launch_bounds(256,2): VGPR cap 256 (acc 64 + frags 64 + misc ~70 fits; a
// tighter bound would spill acc -> r4's 13.9GB disaster).
// MFMA operands (r7/r11-proven): first arg = weights (v rows), scaleA =
// 0x7B..=2^-4 (undoes prep_w's 16x), second = h, scaleB = 0x7F..=1.0.
// C/D: col=lane&15 (m), reg=fq*4+j (v) -> float4 stores (WRITE 513MB ideal).
#define BAR __builtin_amdgcn_s_barrier()
#define LGKM0 asm volatile("s_waitcnt lgkmcnt(0)" ::: "memory")
#define VM8 asm volatile("s_waitcnt vmcnt(8)" ::: "memory")

__global__ __launch_bounds__(256, 2) void gemm_geo(
    const unsigned char* __restrict__ h8, const unsigned char* __restrict__ w8,
    const float* __restrict__ h0, const float* __restrict__ wtime,
    const float* __restrict__ ls, float* __restrict__ out) {
  __shared__ __align__(16) char smem[65536];  // 2 x 32KB

  const int t = threadIdx.x;
  const int wave = t >> 6, lane = t & 63;
  const int fr = lane & 15, fq = lane >> 4;
  const int wm = wave >> 1, wn = wave & 1;  // 2 (M) x 2 (N) wave grid

  // XCD-bijective grid: 8000 blocks (250 v-tiles x 32 m-tiles), 1000/XCD;
  // 32 consecutive blocks per XCD share one 128KB B-panel (L2 reuse), and
  // those 32 m-tiles cover all of A (4MB, L2-resident).
  const int bid = blockIdx.x;
  const int swz = (bid & 7) * 1000 + (bid >> 3);
  const int tile_v = swz >> 5;   // [0,250)
  const int tile_m = swz & 31;   // [0,32)
  const int row0 = tile_m * 128;
  const int col0 = tile_v * 128;

  // read-side lane constants (bytes)
  const int xorv = fr & 7;
  const int c0 = ((2 * fq) ^ xorv) * 16;
  const int c1 = ((2 * fq + 1) ^ xorv) * 16;
  const int a_rd = (wm * 64 + fr) * 128;           // + cbo + im*2048
  const int b_rd = 16384 + (wn * 64 + fr) * 128;   // + cbo + iv*2048

  auto RDF = [&](int off) -> int8v {
    int4v lo = *(const int4v*)(smem + off + c0);
    int4v hi = *(const int4v*)(smem + off + c1);
    return (int8v){lo[0], lo[1], lo[2], lo[3], hi[0], hi[1], hi[2], hi[3]};
  };

  // staging: thread t -> row hh*32 + (t>>3), slot chunk t&7, pre-swizzled
  const int cc = (t & 7) ^ ((t >> 3) & 7);
  const unsigned char* pA = h8 + ((long)row0 + (t >> 3)) * K_TOT + cc * 16;
  const unsigned char* pB = w8 + ((long)col0 + (t >> 3)) * K_TOT + cc * 16;
  const int dst_w = wave * 1024;  // wave-uniform; HW adds lane*16

  auto STAGE = [&](int kt, int bufo) {
#pragma unroll
    for (int hh = 0; hh < 4; ++hh) {
      gload_lds16(pA + (long)hh * (32L * K_TOT) + kt * 128,
                  smem + bufo + hh * 4096 + dst_w);
      gload_lds16(pB + (long)hh * (32L * K_TOT) + kt * 128,
                  smem + bufo + 16384 + hh * 4096 + dst_w);
    }
  };

  f32x4 acc[4][4];
#pragma unroll
  for (int i = 0; i < 4; ++i)
#pragma unroll
    for (int j = 0; j < 4; ++j) acc[i][j] = (f32x4)(0.0f);

  // prologue: tiles 0,1 -> bufs 0,1 (8 loads each); VM8 proves tile0.
  STAGE(0, 0);
  STAGE(1, 32768);
  VM8;
  BAR;

#pragma unroll 1
  for (int kt = 0; kt < 8; ++kt) {
    const int cbo = (kt & 1) << 15;
    const int skt = (kt + 2 < 8) ? kt + 2 : 7;  // clamped redundant tail

    int8v bv[4], av[2];
#pragma unroll
    for (int iv = 0; iv < 4; ++iv) bv[iv] = RDF(cbo + b_rd + iv * 2048);
#pragma unroll
    for (int im = 0; im < 2; ++im) av[im] = RDF(cbo + a_rd + im * 2048);

    __builtin_amdgcn_s_setprio(1);
#pragma unroll
    for (int im = 0; im < 2; ++im)
#pragma unroll
      for (int iv = 0; iv < 4; ++iv)
        acc[im][iv] = __builtin_amdgcn_mfma_scale_f32_16x16x128_f8f6f4(
            bv[iv], av[im], acc[im][iv], 0, 0, 0, 0x7B7B7B7B, 0, 0x7F7F7F7F);
    __builtin_amdgcn_s_setprio(0);

    int8v av2[2];
#pragma unroll
    for (int im = 0; im < 2; ++im)
      av2[im] = RDF(cbo + a_rd + (2 + im) * 2048);
    LGKM0;
    __builtin_amdgcn_sched_barrier(0);
    BAR;  // all waves done reading buf cbo -> safe to overwrite it

    STAGE(skt, cbo);  // tile kt+2 -> same-parity buffer (double buffer)

    __builtin_amdgcn_s_setprio(1);
#pragma unroll
    for (int im = 0; im < 2; ++im)
#pragma unroll
      for (int iv = 0; iv < 4; ++iv)
        acc[2 + im][iv] = __builtin_amdgcn_mfma_scale_f32_16x16x128_f8f6f4(
            bv[iv], av2[im], acc[2 + im][iv], 0, 0, 0, 0x7B7B7B7B, 0,
            0x7F7F7F7F);
    __builtin_amdgcn_s_setprio(0);

    // proves tile kt+1 landed (its 8 loads are >=8 back; kt+2's 8 in flight)
    VM8;
    BAR;
  }

  // fused epilogue (r7/r11-proven): x = h0*w_time - dot; d2 = acosh(x)^2;
  // out = -tau*d2. v on acc-reg axis -> float4 stores. With 2 blocks/CU the
  // other block's K-loop hides this drain.
  const float ntau = -fminf(fmaxf(ls[0], 0.01f), 2.5f);
  const float LN2 = 0.69314718055994531f;
  f32x4 wt4[4];
#pragma unroll
  for (int iv = 0; iv < 4; ++iv)
    wt4[iv] = *(const f32x4*)&wtime[col0 + wn * 64 + iv * 16 + fq * 4];
#pragma unroll
  for (int im = 0; im < 4; ++im) {
    const float hh = h0[row0 + wm * 64 + im * 16 + fr];
    float* orow =
        out + (long)(row0 + wm * 64 + im * 16 + fr) * V_TOT + col0 + wn * 64;
#pragma unroll
    for (int iv = 0; iv < 4; ++iv) {
      f32x4 r;
#pragma unroll
      for (int j = 0; j < 4; ++j) {
        float x = fmaf(hh, wt4[iv][j], -acc[im][iv][j]);
        float xm1 = fmaxf(x - 1.0f, 0.0f);
        float arg = fmaxf(fmaf(x, x, -1.0f), 0.0f);
        float lg2 = __builtin_amdgcn_logf(x + __builtin_amdgcn_sqrtf(arg));
        float dex = LN2 * lg2;
        float d2_exact = dex * dex;
        float ts = fmaf(xm1, -1.0f / 12.0f, 1.0f);
        float d2_tay = 2.0f * xm1 * ts * ts;
        float d2 = (xm1 < 1e-3f) ? d2_tay : d2_exact;
        r[j] = ntau * d2;
      }
      *(f32x4*)(orow + iv * 16 + fq * 4) = r;
    }
  }
}

extern "C" void kernel_launch(void* const* d_in, const int* in_sizes, int n_in,
                              void* d_out, int out_size, void* d_ws, size_t ws_size,
                              hipStream_t stream) {
  const float* h = (const float*)d_in[0];   // [2,2048,1025]
  const float* w = (const float*)d_in[1];   // [32000,1024]
  const float* ls = (const float*)d_in[2];  // scalar
  float* out = (float*)d_out;               // [2,2048,32000] fp32

  char* ws = (char*)d_ws;
  unsigned char* w8 = (unsigned char*)ws;                     // 32,768,000 B
  unsigned char* h8 = (unsigned char*)(ws + 32768000);        // 4,194,304 B
  float* wtime = (float*)(ws + 32768000 + 4194304);           // 128,000 B
  float* h0 = (float*)(ws + 32768000 + 4194304 + 128000);     // 16,384 B

  prep_h<<<M_TOT, 256, 0, stream>>>(h, h8, h0);
  prep_w<<<V_TOT, 256, 0, stream>>>(w, w8, wtime);
  gemm_geo<<<8000, 256, 0, stream>>>(h8, w8, h0, wtime, ls, out);
}

// Round 14
// 273.520 us; speedup vs baseline: 1.2220x; 1.2104x over previous
//
#include <hip/hip_runtime.h>
#include <hip/hip_bf16.h>
#include <hip/hip_fp8.h>
#include <math.h>

#define M_TOT 4096
#define K_TOT 1024
#define V_TOT 32000

typedef int int4v __attribute__((ext_vector_type(4)));
typedef int int8v __attribute__((ext_vector_type(8)));
typedef float f32x4 __attribute__((ext_vector_type(4)));

__device__ __forceinline__ void gload_lds16(const void* g, void* l) {
  __builtin_amdgcn_global_load_lds(
      (const __attribute__((address_space(1))) void*)g,
      (__attribute__((address_space(3))) void*)l, 16, 0, 0);
}

__device__ __forceinline__ float sani(float v) {
  return (v != v) ? 0.0f : fminf(fmaxf(v, -1e4f), 1e4f);
}

__device__ __forceinline__ int pk4_fp8(float a, float b, float c, float d) {
#if __has_builtin(__builtin_amdgcn_cvt_pk_fp8_f32)
  int p = __builtin_amdgcn_cvt_pk_fp8_f32(a, b, 0, false);
  p = __builtin_amdgcn_cvt_pk_fp8_f32(c, d, p, true);
  return p;
#else
  union { unsigned char b4[4]; int i; } u;
  u.b4[0] = __hip_fp8_e4m3(a).__x;
  u.b4[1] = __hip_fp8_e4m3(b).__x;
  u.b4[2] = __hip_fp8_e4m3(c).__x;
  u.b4[3] = __hip_fp8_e4m3(d).__x;
  return u.i;
#endif
}

__global__ void prep_h(const float* __restrict__ h, unsigned char* __restrict__ h8,
                       float* __restrict__ h0) {
  int m = blockIdx.x;
  int t = threadIdx.x;
  const float* row = h + (long)m * (K_TOT + 1);
  if (t == 0) h0[m] = sani(row[0]);
  float4 x = *(const float4*)(row + 1 + t * 4);
  ((int*)(h8 + (long)m * K_TOT))[t] =
      pk4_fp8(sani(x.x), sani(x.y), sani(x.z), sani(x.w));
}

__global__ void prep_w(const float* __restrict__ w, unsigned char* __restrict__ w8,
                       float* __restrict__ wtime) {
  __shared__ float red[4];
  __shared__ float r_sh;
  int v = blockIdx.x;
  int t = threadIdx.x;
  const float* row = w + (long)v * K_TOT;
  float4 x = *(const float4*)(row + t * 4);
  float s = x.x * x.x + x.y * x.y + x.z * x.z + x.w * x.w;
#pragma unroll
  for (int off = 32; off > 0; off >>= 1) s += __shfl_down(s, off);
  int lane = t & 63, wv = t >> 6;
  if (lane == 0) red[wv] = s;
  __syncthreads();
  if (t == 0) {
    float tot = red[0] + red[1] + red[2] + red[3];
    float norm = sqrtf(tot);
    float r = (norm > 1e-7f) ? (sinhf(norm) / fmaxf(norm, 1e-7f)) : 1.0f;
    r_sh = r;
    wtime[v] = coshf(norm);
  }
  __syncthreads();
  float sc = 16.0f * r_sh;
  ((int*)(w8 + (long)v * K_TOT))[t] =
      pk4_fp8(sc * x.x, sc * x.y, sc * x.z, sc * x.w);
}

// ====== 256x256 tile, BK=128, MX-fp8 double-buffered GEMM (r11) ============
// r11 (best: 290us total) verbatim, ONE change: nontemporal float4 epilogue
// stores. Theory: the 512MB write stream through L2 evicts the L2-resident
// A copy + B panels (FETCH 355MB vs ~70MB ideal). nt keeps writes out of
// L2. r6's nt write-amplification was from SCALAR 4B nt stores (partial 64B
// sectors); here 4 lanes x float4 = full 64B lines per (row,iv) -> no amp.
// r13 lesson: 128^2 tile (2 blocks/CU) doubles per-output staging traffic
// -> net loss (331us). Keep 256^2 at 1 block/CU.
// LDS (128 KB): buf*65536 + {A: row*128 + c*16} + {B: 32768 + row*128 + c*16}
// Zero-conflict swizzle (measured ~0): slot chunk c holds global chunk
// c^(row&7); source pre-swizzled cc=(t&7)^((t>>3)&7); read (2fq+h)^(fr&7).
// Loop: reads -> MFMA m0-3 -> reads av4-7 -> lgkm0+schedbar+BAR -> STAGE
// kt+2 into cb -> MFMA m4-7 -> VM8 -> BAR. launch_bounds(512,2) (VGPR 256;
// (512,4) would cap 64 -> acc spill -> r4 disaster).
#define BAR __builtin_amdgcn_s_barrier()
#define LGKM0 asm volatile("s_waitcnt lgkmcnt(0)" ::: "memory")
#define VM8 asm volatile("s_waitcnt vmcnt(8)" ::: "memory")

__global__ __launch_bounds__(512, 2) void gemm_geo(
    const unsigned char* __restrict__ h8, const unsigned char* __restrict__ w8,
    const float* __restrict__ h0, const float* __restrict__ wtime,
    const float* __restrict__ ls, float* __restrict__ out) {
  __shared__ __align__(16) char smem[131072];

  const int t = threadIdx.x;
  const int wave = t >> 6, lane = t & 63;
  const int fr = lane & 15, fq = lane >> 4;
  const int wm = wave >> 2, wn = wave & 3;  // 2 (M) x 4 (N) wave grid

  // XCD-bijective grid: 2000 blocks (125 v-tiles x 16 m-tiles), 250/XCD;
  // 16 consecutive blocks share one B-panel (spatial L2 reuse, r5-proven).
  const int bid = blockIdx.x;
  const int swz = (bid & 7) * 250 + (bid >> 3);
  const int tile_v = swz >> 4;
  const int tile_m = swz & 15;
  const int row0 = tile_m * 256;
  const int col0 = tile_v * 256;

  // read-side lane constants (bytes)
  const int xorv = fr & 7;
  const int c0 = ((2 * fq) ^ xorv) * 16;
  const int c1 = ((2 * fq + 1) ^ xorv) * 16;
  const int a_rd = (wm * 128 + fr) * 128;          // + cbo + im*2048
  const int b_rd = 32768 + (wn * 64 + fr) * 128;   // + cbo + iv*2048

  auto RDF = [&](int off) -> int8v {
    int4v lo = *(const int4v*)(smem + off + c0);
    int4v hi = *(const int4v*)(smem + off + c1);
    return (int8v){lo[0], lo[1], lo[2], lo[3], hi[0], hi[1], hi[2], hi[3]};
  };

  // staging: thread t -> row t>>3 (+64/batch), slot chunk t&7; source chunk
  // pre-swizzled
  const int cc = (t & 7) ^ ((t >> 3) & 7);
  const unsigned char* pA = h8 + ((long)row0 + (t >> 3)) * K_TOT + cc * 16;
  const unsigned char* pB = w8 + ((long)col0 + (t >> 3)) * K_TOT + cc * 16;
  const int dst_w = wave * 1024;  // wave-uniform; HW adds lane*16

  auto STAGE = [&](int kt, int bufo) {
#pragma unroll
    for (int hh = 0; hh < 4; ++hh) {
      gload_lds16(pA + (long)hh * 65536 + kt * 128,
                  smem + bufo + hh * 8192 + dst_w);
      gload_lds16(pB + (long)hh * 65536 + kt * 128,
                  smem + bufo + 32768 + hh * 8192 + dst_w);
    }
  };

  f32x4 acc[8][4];
#pragma unroll
  for (int i = 0; i < 8; ++i)
#pragma unroll
    for (int j = 0; j < 4; ++j) acc[i][j] = (f32x4)(0.0f);

  // prologue: tiles 0,1 -> bufs 0,1 (8 loads each); VM8 proves tile0.
  STAGE(0, 0);
  STAGE(1, 65536);
  VM8;
  BAR;

#pragma unroll 1
  for (int kt = 0; kt < 8; ++kt) {
    const int cbo = (kt & 1) << 16;
    const int skt = (kt + 2 < 8) ? kt + 2 : 7;  // clamped redundant tail

    int8v bv[4], av[4];
#pragma unroll
    for (int iv = 0; iv < 4; ++iv) bv[iv] = RDF(cbo + b_rd + iv * 2048);
#pragma unroll
    for (int im = 0; im < 4; ++im) av[im] = RDF(cbo + a_rd + im * 2048);

    __builtin_amdgcn_s_setprio(1);
#pragma unroll
    for (int im = 0; im < 4; ++im)
#pragma unroll
      for (int iv = 0; iv < 4; ++iv)
        acc[im][iv] = __builtin_amdgcn_mfma_scale_f32_16x16x128_f8f6f4(
            bv[iv], av[im], acc[im][iv], 0, 0, 0, 0x7B7B7B7B, 0, 0x7F7F7F7F);
    __builtin_amdgcn_s_setprio(0);

    int8v av2[4];
#pragma unroll
    for (int im = 0; im < 4; ++im)
      av2[im] = RDF(cbo + a_rd + (4 + im) * 2048);
    LGKM0;
    __builtin_amdgcn_sched_barrier(0);
    BAR;  // all waves done reading buf cbo -> safe to overwrite it

    STAGE(skt, cbo);  // tile kt+2 -> same-parity buffer (double buffer)

    __builtin_amdgcn_s_setprio(1);
#pragma unroll
    for (int im = 0; im < 4; ++im)
#pragma unroll
      for (int iv = 0; iv < 4; ++iv)
        acc[4 + im][iv] = __builtin_amdgcn_mfma_scale_f32_16x16x128_f8f6f4(
            bv[iv], av2[im], acc[4 + im][iv], 0, 0, 0, 0x7B7B7B7B, 0,
            0x7F7F7F7F);
    __builtin_amdgcn_s_setprio(0);

    // proves tile kt+1 landed (its 8 loads are >=8 back; kt+2's 8 in flight)
    VM8;
    BAR;
  }

  // fused epilogue: x = h0*w_time - dot; d2 = acosh(x)^2; out = -tau*d2.
  // v on acc-reg axis -> float4 stores; NONTEMPORAL: full 64B lines (4 lanes
  // x 16B contiguous per row) bypass L2 so the write stream stops evicting
  // the A/B-panel working set.
  const float ntau = -fminf(fmaxf(ls[0], 0.01f), 2.5f);
  const float LN2 = 0.69314718055994531f;
  f32x4 wt4[4];
#pragma unroll
  for (int iv = 0; iv < 4; ++iv)
    wt4[iv] = *(const f32x4*)&wtime[col0 + wn * 64 + iv * 16 + fq * 4];
#pragma unroll
  for (int im = 0; im < 8; ++im) {
    const float hh = h0[row0 + wm * 128 + im * 16 + fr];
    float* orow =
        out + (long)(row0 + wm * 128 + im * 16 + fr) * V_TOT + col0 + wn * 64;
#pragma unroll
    for (int iv = 0; iv < 4; ++iv) {
      f32x4 r;
#pragma unroll
      for (int j = 0; j < 4; ++j) {
        float x = fmaf(hh, wt4[iv][j], -acc[im][iv][j]);
        float xm1 = fmaxf(x - 1.0f, 0.0f);
        float arg = fmaxf(fmaf(x, x, -1.0f), 0.0f);
        float lg2 = __builtin_amdgcn_logf(x + __builtin_amdgcn_sqrtf(arg));
        float dex = LN2 * lg2;
        float d2_exact = dex * dex;
        float ts = fmaf(xm1, -1.0f / 12.0f, 1.0f);
        float d2_tay = 2.0f * xm1 * ts * ts;
        float d2 = (xm1 < 1e-3f) ? d2_tay : d2_exact;
        r[j] = ntau * d2;
      }
      __builtin_nontemporal_store(r, (f32x4*)(orow + iv * 16 + fq * 4));
    }
  }
}

extern "C" void kernel_launch(void* const* d_in, const int* in_sizes, int n_in,
                              void* d_out, int out_size, void* d_ws, size_t ws_size,
                              hipStream_t stream) {
  const float* h = (const float*)d_in[0];   // [2,2048,1025]
  const float* w = (const float*)d_in[1];   // [32000,1024]
  const float* ls = (const float*)d_in[2];  // scalar
  float* out = (float*)d_out;               // [2,2048,32000] fp32

  char* ws = (char*)d_ws;
  unsigned char* w8 = (unsigned char*)ws;                     // 32,768,000 B
  unsigned char* h8 = (unsigned char*)(ws + 32768000);        // 4,194,304 B
  float* wtime = (float*)(ws + 32768000 + 4194304);           // 128,000 B
  float* h0 = (float*)(ws + 32768000 + 4194304 + 128000);     // 16,384 B

  prep_h<<<M_TOT, 256, 0, stream>>>(h, h8, h0);
  prep_w<<<V_TOT, 256, 0, stream>>>(w, w8, wtime);
  gemm_geo<<<2000, 512, 0, stream>>>(h8, w8, h0, wtime, ls, out);
}